// Round 1
// baseline (103.053 us; speedup 1.0000x reference)
//
#include <hip/hip_runtime.h>
#include <math.h>

// Problem constants (fixed by the reference setup)
#define B_ 32
#define N_ 2048
#define D_ 64
#define R_ 32
#define T_ 31
#define O_ 12
#define HID_ 128
#define IN_DIM_ 63      // T_ + R_
#define NCH_ 8          // n-chunks for partial-U reduction
#define NC_ 64          // n rows per block in main kernel

// Workspace layout (float offsets)
#define OFF_QSP   0
#define OFF_PSP   (N_*R_)                        // 65536
#define OFF_UPART (OFF_PSP + N_*R_)              // 131072
#define OFF_U     (OFF_UPART + B_*NCH_*R_*D_)    // 655360
#define OFF_CTX   (OFF_U + B_*R_*D_)             // 720896
#define OFF_SUA   (OFF_CTX + B_*R_)              // 721920
// total floats = OFF_SUA + B_*O_*R_*D_ = 1,508,352  (~5.8 MB)

__device__ __forceinline__ float softplus_f(float x) {
    // logaddexp(x, 0) = max(x,0) + log1p(exp(-|x|))
    return fmaxf(x, 0.0f) + log1pf(expf(-fabsf(x)));
}
__device__ __forceinline__ float gelu_f(float x) {
    // exact gelu: 0.5*x*(1+erf(x/sqrt(2)))
    return 0.5f * x * (1.0f + erff(x * 0.70710678118654752440f));
}

// Kernel 1: softplus(Q_raw) -> Qsp, softplus(P_raw) -> Psp
__global__ __launch_bounds__(256) void k_softplus(const float* __restrict__ Qr,
                                                  const float* __restrict__ Pr,
                                                  float* __restrict__ ws) {
    int i = blockIdx.x * blockDim.x + threadIdx.x;
    if (i < N_ * R_) {
        ws[OFF_QSP + i] = softplus_f(Qr[i]);
    } else if (i < 2 * N_ * R_) {
        int j = i - N_ * R_;
        ws[OFF_PSP + j] = softplus_f(Pr[j]);
    }
}

// Kernel 2a: partial U over n-chunks. grid = B_*NCH_ blocks, 512 threads.
// thread: d = tid&63, rb = tid>>6 (wave-uniform), r in {rb, rb+8, rb+16, rb+24}
__global__ __launch_bounds__(512) void k_upart(const float* __restrict__ H,
                                               float* __restrict__ ws) {
    const float* __restrict__ Qsp = ws + OFF_QSP;
    float* __restrict__ Upart = ws + OFF_UPART;
    int b = blockIdx.x / NCH_;
    int c = blockIdx.x % NCH_;
    int tid = threadIdx.x;
    int d = tid & 63;
    int rb = __builtin_amdgcn_readfirstlane(tid >> 6);  // 0..7, wave-uniform
    float acc0 = 0.f, acc1 = 0.f, acc2 = 0.f, acc3 = 0.f;
    const int n0 = c * (N_ / NCH_);
    const float* __restrict__ Hb = H + (size_t)b * N_ * D_;
    for (int n = n0; n < n0 + N_ / NCH_; ++n) {
        float h = Hb[n * D_ + d];
        const float* q = Qsp + n * R_ + rb;   // uniform address -> s_load
        acc0 += h * q[0];
        acc1 += h * q[8];
        acc2 += h * q[16];
        acc3 += h * q[24];
    }
    float* up = Upart + ((size_t)(b * NCH_ + c) * R_) * D_ + d;
    up[(rb + 0) * D_]  = acc0;
    up[(rb + 8) * D_]  = acc1;
    up[(rb + 16) * D_] = acc2;
    up[(rb + 24) * D_] = acc3;
}

// Kernel 2b: reduce partials -> U, compute ctx = sqrt(mean_d U^2 + eps)
__global__ __launch_bounds__(512) void k_ured(float* __restrict__ ws) {
    const float* __restrict__ Upart = ws + OFF_UPART;
    float* __restrict__ U = ws + OFF_U;
    float* __restrict__ ctx = ws + OFF_CTX;
    int b = blockIdx.x;
    int tid = threadIdx.x;
    int d = tid & 63;
    int rb = tid >> 6;
    #pragma unroll
    for (int j = 0; j < 4; ++j) {
        int r = rb + 8 * j;
        float u = 0.f;
        #pragma unroll
        for (int c = 0; c < NCH_; ++c)
            u += Upart[((size_t)(b * NCH_ + c) * R_ + r) * D_ + d];
        U[((size_t)b * R_ + r) * D_ + d] = u;
        float sq = u * u;
        #pragma unroll
        for (int off = 32; off; off >>= 1) sq += __shfl_xor(sq, off, 64);
        if (d == 0) ctx[b * R_ + r] = sqrtf(sq * (1.0f / D_) + 1e-6f);
    }
}

// Kernel 3: per (b,o): feat -> gelu(feat@W1+b1) -> softplus(h@W2+b2)=s,
// then SUa[b,o,r,d] = a * s[r] * U[b,r,d].  grid = B_*O_, 128 threads.
__global__ __launch_bounds__(128) void k_mlp(const float* __restrict__ ts_out,
                                             const float* __restrict__ W1,
                                             const float* __restrict__ b1,
                                             const float* __restrict__ W2,
                                             const float* __restrict__ b2,
                                             const float* __restrict__ alpha,
                                             float* __restrict__ ws) {
    __shared__ float feat[IN_DIM_];
    __shared__ float hsh[HID_];
    __shared__ float ssh[R_];
    int bo = blockIdx.x;
    int b = bo / O_;
    int tid = threadIdx.x;
    const float* __restrict__ ctx = ws + OFF_CTX;
    if (tid < T_) feat[tid] = ts_out[(size_t)bo * T_ + tid];
    else if (tid < IN_DIM_) feat[tid] = ctx[b * R_ + (tid - T_)];
    __syncthreads();
    float acc = b1[tid];
    #pragma unroll 9
    for (int k = 0; k < IN_DIM_; ++k) acc += feat[k] * W1[k * HID_ + tid];
    hsh[tid] = gelu_f(acc);
    __syncthreads();
    if (tid < R_) {
        float a2 = b2[tid];
        #pragma unroll 8
        for (int j = 0; j < HID_; ++j) a2 += hsh[j] * W2[j * R_ + tid];
        ssh[tid] = softplus_f(a2);
    }
    __syncthreads();
    float a = fminf(fmaxf(alpha[0], 0.0f), 1.0f);
    const float* __restrict__ U = ws + OFF_U;
    float* __restrict__ SUa = ws + OFF_SUA;
    #pragma unroll
    for (int idx = tid; idx < R_ * D_; idx += 128) {
        int r = idx >> 6, d = idx & 63;
        SUa[((size_t)bo * R_ + r) * D_ + d] = a * ssh[r] * U[((size_t)b * R_ + r) * D_ + d];
    }
}

// Kernel 4: out[b,o,n,d] = (1-a)*H[b,n,d] + sum_r Psp[n,r]*SUa[b,o,r,d]
// grid = (N_/NC_, B_), block 256 (4 waves). lane=d; wave w owns o in {3w..3w+2};
// n is wave-uniform -> Psp row comes in via s_load (scalar operand to v_fmac).
__global__ __launch_bounds__(256) void k_main(const float* __restrict__ H,
                                              const float* __restrict__ alpha,
                                              const float* __restrict__ ws,
                                              float* __restrict__ out) {
    const float* __restrict__ Psp = ws + OFF_PSP;
    const float* __restrict__ SUa = ws + OFF_SUA;
    int b = blockIdx.y;
    int nbase = blockIdx.x * NC_;
    int tid = threadIdx.x;
    int lane = tid & 63;
    int w = __builtin_amdgcn_readfirstlane(tid >> 6);  // 0..3
    float a = fminf(fmaxf(alpha[0], 0.0f), 1.0f);
    float oma = 1.0f - a;

    // Pre-load this wave's 3 o-slices of SUa: su[oi][r] (96 VGPRs)
    float su[3][R_];
    #pragma unroll
    for (int oi = 0; oi < 3; ++oi) {
        int o = w * 3 + oi;
        const float* sp = SUa + ((size_t)(b * O_ + o) * R_) * D_ + lane;
        #pragma unroll
        for (int r = 0; r < R_; ++r) su[oi][r] = sp[r * D_];
    }

    const float* __restrict__ Hb = H + ((size_t)b * N_ + nbase) * D_ + lane;
    const int o0 = w * 3;
    float* out0 = out + ((size_t)(b * O_ + o0) * N_ + nbase) * D_ + lane;

    for (int ni = 0; ni < NC_; ++ni) {
        int n = nbase + ni;
        float hv = Hb[ni * D_];
        const float* pp = Psp + n * R_;   // uniform address -> s_load x32
        float acc0 = oma * hv, acc1 = oma * hv, acc2 = oma * hv;
        #pragma unroll
        for (int r = 0; r < R_; ++r) {
            float p = pp[r];
            acc0 += p * su[0][r];
            acc1 += p * su[1][r];
            acc2 += p * su[2][r];
        }
        out0[(size_t)0 * N_ * D_ + ni * D_] = acc0;
        out0[(size_t)1 * N_ * D_ + ni * D_] = acc1;
        out0[(size_t)2 * N_ * D_ + ni * D_] = acc2;
    }
}

extern "C" void kernel_launch(void* const* d_in, const int* in_sizes, int n_in,
                              void* d_out, int out_size, void* d_ws, size_t ws_size,
                              hipStream_t stream) {
    const float* H      = (const float*)d_in[0];
    const float* ts_out = (const float*)d_in[1];
    // d_in[2] is O (int scalar) — shapes are compile-time constants here
    const float* P_raw  = (const float*)d_in[3];
    const float* Q_raw  = (const float*)d_in[4];
    const float* W1     = (const float*)d_in[5];
    const float* b1     = (const float*)d_in[6];
    const float* W2     = (const float*)d_in[7];
    const float* b2     = (const float*)d_in[8];
    const float* alpha  = (const float*)d_in[9];
    float* out = (float*)d_out;
    float* ws  = (float*)d_ws;

    // 1. softplus of Q_raw and P_raw
    k_softplus<<<dim3((2 * N_ * R_ + 255) / 256), dim3(256), 0, stream>>>(Q_raw, P_raw, ws);
    // 2a. partial U
    k_upart<<<dim3(B_ * NCH_), dim3(512), 0, stream>>>(H, ws);
    // 2b. reduce U + ctx
    k_ured<<<dim3(B_), dim3(512), 0, stream>>>(ws);
    // 3. MLP -> s -> SUa
    k_mlp<<<dim3(B_ * O_), dim3(128), 0, stream>>>(ts_out, W1, b1, W2, b2, alpha, ws);
    // 4. main fused output
    k_main<<<dim3(N_ / NC_, B_), dim3(256), 0, stream>>>(H, alpha, ws, out);
}